// Round 1
// baseline (227.842 us; speedup 1.0000x reference)
//
#include <hip/hip_runtime.h>

// GRU trajectory decoder, fused single kernel.
// B=16384, D=256, HID=128, T=60, O=3.
// Block: 512 threads = 8 waves; block owns 16 batch rows for all 60 steps.
// Wave w owns hidden dims [16w, 16w+16): N-tiles {r,z,n} x 4 K-tiles of
// mfma_f32_16x16x32_bf16. W_hh fragments + gi (as MFMA C-init) stay in
// registers; h goes through a double-buffered, XOR-swizzled LDS tile.

typedef __attribute__((ext_vector_type(8))) short short8;
typedef __attribute__((ext_vector_type(4))) float f32x4;

#define MFMA16(a, b, c) __builtin_amdgcn_mfma_f32_16x16x32_bf16((a), (b), (c), 0, 0, 0)

__device__ __forceinline__ short f2bf(float x) {
    union { float f; unsigned u; } v; v.f = x;
    unsigned r = v.u + 0x7FFFu + ((v.u >> 16) & 1u);   // RNE
    return (short)(r >> 16);
}

__device__ __forceinline__ short8 cvt8(const float* __restrict__ p) {
    f32x4 a = *(const f32x4*)p;
    f32x4 b = *(const f32x4*)(p + 4);
    short8 r;
    r[0] = f2bf(a[0]); r[1] = f2bf(a[1]); r[2] = f2bf(a[2]); r[3] = f2bf(a[3]);
    r[4] = f2bf(b[0]); r[5] = f2bf(b[1]); r[6] = f2bf(b[2]); r[7] = f2bf(b[3]);
    return r;
}

// sigmoid(x) = 1/(1+2^(-x*log2e)); safe at +-inf (no inf/inf)
__device__ __forceinline__ float fsig(float x) {
    float e = __builtin_amdgcn_exp2f(x * -1.442695041f);
    return __builtin_amdgcn_rcpf(1.0f + e);
}
// tanh(x) = 2*sigmoid(2x) - 1
__device__ __forceinline__ float ftanh_(float x) {
    float e = __builtin_amdgcn_exp2f(x * -2.885390082f);
    return 2.0f * __builtin_amdgcn_rcpf(1.0f + e) - 1.0f;
}

__global__ __launch_bounds__(512, 2) void gru_traj_kernel(
    const float* __restrict__ x,      // [B,256]
    const float* __restrict__ W_ih,   // [384,256]
    const float* __restrict__ W_hh,   // [384,128]
    const float* __restrict__ b_ih,   // [384]
    const float* __restrict__ b_hh,   // [384]
    const float* __restrict__ W_out,  // [3,128]
    const float* __restrict__ b_out,  // [3]
    float* __restrict__ out)          // [B,60,3]
{
    const int tid  = threadIdx.x;
    const int wid  = tid >> 6;          // wave 0..7 -> hidden chunk
    const int lane = tid & 63;
    const int l15  = lane & 15;
    const int l4   = lane >> 4;         // 0..3
    const int b0   = blockIdx.x << 4;   // 16 batch rows per block
    const int jloc = (wid << 4) + l15;  // hidden dim 0..127 owned by this lane

    // h as bf16, [16 rows][128 cols], XOR-swizzled in 16B chunks, double buffered
    __shared__ short hbuf[2][16 * 128];

    for (int i = tid; i < 16 * 128; i += 512) hbuf[0][i] = 0;  // h_0 = 0

    // ---- persistent W_hh fragments: B[k][n] = W_hh[g*128 + jloc][k] ----
    short8 wfrag[3][4];
    #pragma unroll
    for (int g = 0; g < 3; ++g) {
        const float* wrow = W_hh + (size_t)(g * 128 + jloc) * 128;
        #pragma unroll
        for (int kt = 0; kt < 4; ++kt)
            wfrag[g][kt] = cvt8(wrow + kt * 32 + l4 * 8);
    }
    // ---- W_out fragments, N padded to 16 (cols n>=3 zero) ----
    short8 wofrag[4];
    #pragma unroll
    for (int kt = 0; kt < 4; ++kt) {
        short8 f = {0, 0, 0, 0, 0, 0, 0, 0};
        if (l15 < 3) f = cvt8(W_out + l15 * 128 + kt * 32 + l4 * 8);
        wofrag[kt] = f;
    }
    const float bo  = (l15 < 3) ? b_out[l15] : 0.0f;
    const float bhn = b_hh[256 + jloc];

    // ---- prologue: gi = x @ W_ih^T + biases, directly in MFMA C/D layout ----
    // r,z tiles fold b_ih+b_hh (gh bias) into C-init; n tile keeps gi_n only.
    f32x4 initR, initZ, giN;
    {
        const float br = b_ih[jloc] + b_hh[jloc];
        const float bz = b_ih[128 + jloc] + b_hh[128 + jloc];
        const float bn = b_ih[256 + jloc];
        initR = (f32x4){br, br, br, br};
        initZ = (f32x4){bz, bz, bz, bz};
        giN   = (f32x4){bn, bn, bn, bn};
        #pragma unroll
        for (int kt = 0; kt < 8; ++kt) {
            short8 af = cvt8(x + (size_t)(b0 + l15) * 256 + kt * 32 + l4 * 8);
            short8 bR = cvt8(W_ih + (size_t)(jloc) * 256 + kt * 32 + l4 * 8);
            short8 bZ = cvt8(W_ih + (size_t)(128 + jloc) * 256 + kt * 32 + l4 * 8);
            short8 bN = cvt8(W_ih + (size_t)(256 + jloc) * 256 + kt * 32 + l4 * 8);
            initR = MFMA16(af, bR, initR);
            initZ = MFMA16(af, bZ, initZ);
            giN   = MFMA16(af, bN, giN);
        }
    }

    float hprev[4] = {0.f, 0.f, 0.f, 0.f};
    const int cbase = jloc >> 3;   // 16B chunk containing this lane's hidden dim
    const int elo   = jloc & 7;

    __syncthreads();

    #pragma unroll 2
    for (int t = 0; t < 60; ++t) {
        const short* rb = hbuf[t & 1];           // h_t
        // A-frags: A[m=l15][k = kt*32 + l4*8 + e], chunk-swizzled read
        short8 af[4];
        #pragma unroll
        for (int kt = 0; kt < 4; ++kt) {
            const int c = ((kt * 4 + l4) ^ l15) & 15;
            af[kt] = *(const short8*)(rb + l15 * 128 + c * 8);
        }
        // output head for timestep t-1 (h_t), rotated across waves
        if (t > 0 && wid == ((t - 1) & 7)) {
            f32x4 oa = (f32x4){0.f, 0.f, 0.f, 0.f};
            #pragma unroll
            for (int kt = 0; kt < 4; ++kt) oa = MFMA16(af[kt], wofrag[kt], oa);
            if (l15 < 3) {
                #pragma unroll
                for (int r = 0; r < 4; ++r)
                    out[(size_t)(b0 + l4 * 4 + r) * 180 + (t - 1) * 3 + l15] = oa[r] + bo;
            }
        }
        // gh = h_t @ W_hh^T (+ folded biases in C-init)
        f32x4 aR = initR, aZ = initZ;
        f32x4 aN = (f32x4){bhn, bhn, bhn, bhn};
        #pragma unroll
        for (int kt = 0; kt < 4; ++kt) {
            aR = MFMA16(af[kt], wfrag[0][kt], aR);
            aZ = MFMA16(af[kt], wfrag[1][kt], aZ);
            aN = MFMA16(af[kt], wfrag[2][kt], aN);
        }
        // gates + state update; write h_{t+1} bf16 to the other buffer
        short* wb = hbuf[(t & 1) ^ 1];
        #pragma unroll
        for (int r = 0; r < 4; ++r) {
            float rr = fsig(aR[r]);
            float zz = fsig(aZ[r]);
            float nn = ftanh_(giN[r] + rr * aN[r]);
            float hn = nn + zz * (hprev[r] - nn);   // (1-z)*n + z*h
            hprev[r] = hn;
            const int row = l4 * 4 + r;
            wb[row * 128 + ((cbase ^ row) & 15) * 8 + elo] = f2bf(hn);
        }
        __syncthreads();
    }

    // epilogue: output for t=59 from h_60 (in hbuf[0])
    if (wid == 3) {
        const short* rb = hbuf[0];
        f32x4 oa = (f32x4){0.f, 0.f, 0.f, 0.f};
        #pragma unroll
        for (int kt = 0; kt < 4; ++kt) {
            const int c = ((kt * 4 + l4) ^ l15) & 15;
            short8 af = *(const short8*)(rb + l15 * 128 + c * 8);
            oa = MFMA16(af, wofrag[kt], oa);
        }
        if (l15 < 3) {
            #pragma unroll
            for (int r = 0; r < 4; ++r)
                out[(size_t)(b0 + l4 * 4 + r) * 180 + 59 * 3 + l15] = oa[r] + bo;
        }
    }
}

extern "C" void kernel_launch(void* const* d_in, const int* in_sizes, int n_in,
                              void* d_out, int out_size, void* d_ws, size_t ws_size,
                              hipStream_t stream) {
    const float* x     = (const float*)d_in[0];
    const float* W_ih  = (const float*)d_in[1];
    const float* W_hh  = (const float*)d_in[2];
    const float* b_ih  = (const float*)d_in[3];
    const float* b_hh  = (const float*)d_in[4];
    const float* W_out = (const float*)d_in[5];
    const float* b_out = (const float*)d_in[6];
    float* out = (float*)d_out;

    const int B = in_sizes[0] / 256;   // 16384
    hipLaunchKernelGGL(gru_traj_kernel, dim3(B / 16), dim3(512), 0, stream,
                       x, W_ih, W_hh, b_ih, b_hh, W_out, b_out, out);
}

// Round 2
// 199.687 us; speedup vs baseline: 1.1410x; 1.1410x over previous
//
#include <hip/hip_runtime.h>

// GRU trajectory decoder, fused single kernel.
// B=16384, D=256, HID=128, T=60, O=3.
// Block: 512 threads = 8 waves; block owns 16 batch rows for all 60 steps.
// Wave w owns hidden dims [16w, 16w+16): N-tiles {r,z,n} x 4 K-tiles of
// mfma_f32_16x16x32_bf16. W_hh fragments + gi (as MFMA C-init) stay in
// registers; h goes through a double-buffered, XOR-swizzled LDS tile.
// R2: W_out fragments moved to LDS; __launch_bounds__(512,4) to fit the
// 128-reg occupancy step -> 2 blocks/CU (was 1, the R1 bottleneck).

typedef __attribute__((ext_vector_type(8))) short short8;
typedef __attribute__((ext_vector_type(4))) float f32x4;

#define MFMA16(a, b, c) __builtin_amdgcn_mfma_f32_16x16x32_bf16((a), (b), (c), 0, 0, 0)

__device__ __forceinline__ short f2bf(float x) {
    union { float f; unsigned u; } v; v.f = x;
    unsigned r = v.u + 0x7FFFu + ((v.u >> 16) & 1u);   // RNE
    return (short)(r >> 16);
}

__device__ __forceinline__ short8 cvt8(const float* __restrict__ p) {
    f32x4 a = *(const f32x4*)p;
    f32x4 b = *(const f32x4*)(p + 4);
    short8 r;
    r[0] = f2bf(a[0]); r[1] = f2bf(a[1]); r[2] = f2bf(a[2]); r[3] = f2bf(a[3]);
    r[4] = f2bf(b[0]); r[5] = f2bf(b[1]); r[6] = f2bf(b[2]); r[7] = f2bf(b[3]);
    return r;
}

// sigmoid(x) = 1/(1+2^(-x*log2e)); safe at +-inf (no inf/inf)
__device__ __forceinline__ float fsig(float x) {
    float e = __builtin_amdgcn_exp2f(x * -1.442695041f);
    return __builtin_amdgcn_rcpf(1.0f + e);
}
// tanh(x) = 2*sigmoid(2x) - 1
__device__ __forceinline__ float ftanh_(float x) {
    float e = __builtin_amdgcn_exp2f(x * -2.885390082f);
    return 2.0f * __builtin_amdgcn_rcpf(1.0f + e) - 1.0f;
}

__global__ __launch_bounds__(512, 4) void gru_traj_kernel(
    const float* __restrict__ x,      // [B,256]
    const float* __restrict__ W_ih,   // [384,256]
    const float* __restrict__ W_hh,   // [384,128]
    const float* __restrict__ b_ih,   // [384]
    const float* __restrict__ b_hh,   // [384]
    const float* __restrict__ W_out,  // [3,128]
    const float* __restrict__ b_out,  // [3]
    float* __restrict__ out)          // [B,60,3]
{
    const int tid  = threadIdx.x;
    const int wid  = tid >> 6;          // wave 0..7 -> hidden chunk
    const int lane = tid & 63;
    const int l15  = lane & 15;
    const int l4   = lane >> 4;         // 0..3
    const int b0   = blockIdx.x << 4;   // 16 batch rows per block
    const int jloc = (wid << 4) + l15;  // hidden dim 0..127 owned by this lane

    // h as bf16, [16 rows][128 cols], XOR-swizzled in 16B chunks, double buffered
    __shared__ short hbuf[2][16 * 128];
    __shared__ short wobuf[3 * 128];    // W_out bf16 [3][128]

    for (int i = tid; i < 16 * 128; i += 512) hbuf[0][i] = 0;  // h_0 = 0
    if (tid < 384) wobuf[tid] = f2bf(W_out[tid]);

    // ---- persistent W_hh fragments: B[k][n] = W_hh[g*128 + jloc][k] ----
    short8 wfrag[3][4];
    #pragma unroll
    for (int g = 0; g < 3; ++g) {
        const float* wrow = W_hh + (size_t)(g * 128 + jloc) * 128;
        #pragma unroll
        for (int kt = 0; kt < 4; ++kt)
            wfrag[g][kt] = cvt8(wrow + kt * 32 + l4 * 8);
    }
    const float bo  = (l15 < 3) ? b_out[l15] : 0.0f;
    const float bhn = b_hh[256 + jloc];

    // ---- prologue: gi = x @ W_ih^T + biases, directly in MFMA C/D layout ----
    // r,z tiles fold b_ih+b_hh (gh bias) into C-init; n tile keeps gi_n only.
    f32x4 initR, initZ, giN;
    {
        const float br = b_ih[jloc] + b_hh[jloc];
        const float bz = b_ih[128 + jloc] + b_hh[128 + jloc];
        const float bn = b_ih[256 + jloc];
        initR = (f32x4){br, br, br, br};
        initZ = (f32x4){bz, bz, bz, bz};
        giN   = (f32x4){bn, bn, bn, bn};
        #pragma unroll
        for (int kt = 0; kt < 8; ++kt) {
            short8 af = cvt8(x + (size_t)(b0 + l15) * 256 + kt * 32 + l4 * 8);
            short8 bR = cvt8(W_ih + (size_t)(jloc) * 256 + kt * 32 + l4 * 8);
            short8 bZ = cvt8(W_ih + (size_t)(128 + jloc) * 256 + kt * 32 + l4 * 8);
            short8 bN = cvt8(W_ih + (size_t)(256 + jloc) * 256 + kt * 32 + l4 * 8);
            initR = MFMA16(af, bR, initR);
            initZ = MFMA16(af, bZ, initZ);
            giN   = MFMA16(af, bN, giN);
        }
    }

    float hprev[4] = {0.f, 0.f, 0.f, 0.f};
    const int cbase = jloc >> 3;   // 16B chunk containing this lane's hidden dim
    const int elo   = jloc & 7;

    __syncthreads();

    #pragma unroll 2
    for (int t = 0; t < 60; ++t) {
        const short* rb = hbuf[t & 1];           // h_t
        // A-frags: A[m=l15][k = kt*32 + l4*8 + e], chunk-swizzled read
        short8 af[4];
        #pragma unroll
        for (int kt = 0; kt < 4; ++kt) {
            const int c = ((kt * 4 + l4) ^ l15) & 15;
            af[kt] = *(const short8*)(rb + l15 * 128 + c * 8);
        }
        // output head for timestep t-1 (h_t), rotated across waves
        if (t > 0 && wid == ((t - 1) & 7)) {
            f32x4 oa = (f32x4){0.f, 0.f, 0.f, 0.f};
            #pragma unroll
            for (int kt = 0; kt < 4; ++kt) {
                short8 wo = (l15 < 3)
                    ? *(const short8*)(wobuf + l15 * 128 + kt * 32 + l4 * 8)
                    : (short8){0, 0, 0, 0, 0, 0, 0, 0};
                oa = MFMA16(af[kt], wo, oa);
            }
            if (l15 < 3) {
                #pragma unroll
                for (int r = 0; r < 4; ++r)
                    out[(size_t)(b0 + l4 * 4 + r) * 180 + (t - 1) * 3 + l15] = oa[r] + bo;
            }
        }
        // gh = h_t @ W_hh^T (+ folded biases in C-init)
        f32x4 aR = initR, aZ = initZ;
        f32x4 aN = (f32x4){bhn, bhn, bhn, bhn};
        #pragma unroll
        for (int kt = 0; kt < 4; ++kt) {
            aR = MFMA16(af[kt], wfrag[0][kt], aR);
            aZ = MFMA16(af[kt], wfrag[1][kt], aZ);
            aN = MFMA16(af[kt], wfrag[2][kt], aN);
        }
        // gates + state update; write h_{t+1} bf16 to the other buffer
        short* wb = hbuf[(t & 1) ^ 1];
        #pragma unroll
        for (int r = 0; r < 4; ++r) {
            float rr = fsig(aR[r]);
            float zz = fsig(aZ[r]);
            float nn = ftanh_(giN[r] + rr * aN[r]);
            float hn = nn + zz * (hprev[r] - nn);   // (1-z)*n + z*h
            hprev[r] = hn;
            const int row = l4 * 4 + r;
            wb[row * 128 + ((cbase ^ row) & 15) * 8 + elo] = f2bf(hn);
        }
        __syncthreads();
    }

    // epilogue: output for t=59 from h_60 (in hbuf[0])
    if (wid == 3) {
        const short* rb = hbuf[0];
        f32x4 oa = (f32x4){0.f, 0.f, 0.f, 0.f};
        #pragma unroll
        for (int kt = 0; kt < 4; ++kt) {
            const int c = ((kt * 4 + l4) ^ l15) & 15;
            short8 af = *(const short8*)(rb + l15 * 128 + c * 8);
            short8 wo = (l15 < 3)
                ? *(const short8*)(wobuf + l15 * 128 + kt * 32 + l4 * 8)
                : (short8){0, 0, 0, 0, 0, 0, 0, 0};
            oa = MFMA16(af, wo, oa);
        }
        if (l15 < 3) {
            #pragma unroll
            for (int r = 0; r < 4; ++r)
                out[(size_t)(b0 + l4 * 4 + r) * 180 + 59 * 3 + l15] = oa[r] + bo;
        }
    }
}

extern "C" void kernel_launch(void* const* d_in, const int* in_sizes, int n_in,
                              void* d_out, int out_size, void* d_ws, size_t ws_size,
                              hipStream_t stream) {
    const float* x     = (const float*)d_in[0];
    const float* W_ih  = (const float*)d_in[1];
    const float* W_hh  = (const float*)d_in[2];
    const float* b_ih  = (const float*)d_in[3];
    const float* b_hh  = (const float*)d_in[4];
    const float* W_out = (const float*)d_in[5];
    const float* b_out = (const float*)d_in[6];
    float* out = (float*)d_out;

    const int B = in_sizes[0] / 256;   // 16384
    hipLaunchKernelGGL(gru_traj_kernel, dim3(B / 16), dim3(512), 0, stream,
                       x, W_ih, W_hh, b_ih, b_hh, W_out, b_out, out);
}

// Round 4
// 167.553 us; speedup vs baseline: 1.3598x; 1.1918x over previous
//
#include <hip/hip_runtime.h>

// GRU trajectory decoder, fused single kernel. B=16384, D=256, HID=128, T=60, O=3.
// R3/R4: transposed compute D = W * h^T. Block = 512 thr (8 waves) owns 64 batch
// rows; grid = 256 = 1 block/CU, ONE round. Wave w owns hid dims [16w,16w+16)
// as MFMA A-rows (W_hh fragments, 48 regs) and iterates 4 batch-chunk tiles
// (4x ILP). Gate outputs are 4 consecutive hid dims of one batch row ->
// h-writeback = 1 ds_write_b64. h lives in a double-buffered LDS tile,
// XOR-swizzled at 16B-chunk granularity (2-way conflicts = free).
// 2 waves/SIMD (256 regs) -- R2 showed 4 waves/SIMD spills ~190 persistent regs.
// R4 fix: hand-rolled bf16 RNE converters (ROCm 7.2 helper overloads failed).

typedef __attribute__((ext_vector_type(8))) short short8;
typedef __attribute__((ext_vector_type(4))) float f32x4;

#define MFMA16(a, b, c) __builtin_amdgcn_mfma_f32_16x16x32_bf16((a), (b), (c), 0, 0, 0)

__device__ __forceinline__ short f2bf(float x) {
    union { float f; unsigned u; } v; v.f = x;
    unsigned r = v.u + 0x7FFFu + ((v.u >> 16) & 1u);   // RNE
    return (short)(r >> 16);
}
__device__ __forceinline__ unsigned pk2bf(float lo, float hi) {
    return ((unsigned)(unsigned short)f2bf(hi) << 16) | (unsigned short)f2bf(lo);
}

__device__ __forceinline__ short8 cvt8(const float* __restrict__ p) {
    f32x4 a = *(const f32x4*)p;
    f32x4 b = *(const f32x4*)(p + 4);
    short8 r;
    r[0] = f2bf(a[0]); r[1] = f2bf(a[1]); r[2] = f2bf(a[2]); r[3] = f2bf(a[3]);
    r[4] = f2bf(b[0]); r[5] = f2bf(b[1]); r[6] = f2bf(b[2]); r[7] = f2bf(b[3]);
    return r;
}

// sigmoid(x) = 1/(1+2^(-x*log2e)); safe at +-inf
__device__ __forceinline__ float fsig(float x) {
    float e = __builtin_amdgcn_exp2f(x * -1.442695041f);
    return __builtin_amdgcn_rcpf(1.0f + e);
}
// tanh(x) = 2*sigmoid(2x) - 1
__device__ __forceinline__ float ftanh_(float x) {
    float e = __builtin_amdgcn_exp2f(x * -2.885390082f);
    return 2.0f * __builtin_amdgcn_rcpf(1.0f + e) - 1.0f;
}

__global__ __launch_bounds__(512, 2) void gru_traj_kernel(
    const float* __restrict__ x,      // [B,256]
    const float* __restrict__ W_ih,   // [384,256]
    const float* __restrict__ W_hh,   // [384,128]
    const float* __restrict__ b_ih,   // [384]
    const float* __restrict__ b_hh,   // [384]
    const float* __restrict__ W_out,  // [3,128]
    const float* __restrict__ b_out,  // [3]
    float* __restrict__ out)          // [B,60,3]
{
    const int tid  = threadIdx.x;
    const int wid  = tid >> 6;          // wave 0..7 -> hid chunk
    const int lane = tid & 63;
    const int l15  = lane & 15;
    const int l4   = lane >> 4;         // 0..3
    const int b0   = blockIdx.x << 6;   // 64 batch rows per block
    const int hb   = wid << 4;          // wave's 16 hidden dims

    // h^T staging: [64 batch rows][128 hid] bf16, 16B-chunk XOR swizzle, dbuf
    __shared__ short hbuf[2][64 * 128];
    __shared__ short wobuf[3 * 136];    // W_out bf16, padded rows (bank-conflict-free)

    {   // h_0 = 0
        int* z = (int*)hbuf[0];
        #pragma unroll
        for (int i = 0; i < 8; ++i) z[tid + i * 512] = 0;
    }
    if (tid < 384) wobuf[(tid >> 7) * 136 + (tid & 127)] = f2bf(W_out[tid]);

    // ---- persistent W_hh A-frags: A[m=l15][k] = W_hh[g*128 + hb + l15][k] ----
    short8 wfrag[3][4];
    #pragma unroll
    for (int g = 0; g < 3; ++g)
        #pragma unroll
        for (int kt = 0; kt < 4; ++kt)
            wfrag[g][kt] = cvt8(W_hh + (size_t)(g * 128 + hb + l15) * 128 + kt * 32 + l4 * 8);

    // biases as f32x4 over this lane's 4 hid dims (rows l4*4+r of the D-tile)
    const f32x4 bR4  = *(const f32x4*)(b_ih +       hb + l4 * 4) + *(const f32x4*)(b_hh +       hb + l4 * 4);
    const f32x4 bZ4  = *(const f32x4*)(b_ih + 128 + hb + l4 * 4) + *(const f32x4*)(b_hh + 128 + hb + l4 * 4);
    const f32x4 bN4i = *(const f32x4*)(b_ih + 256 + hb + l4 * 4);
    const f32x4 bN4h = *(const f32x4*)(b_hh + 256 + hb + l4 * 4);
    const float bo0 = b_out[0], bo1 = b_out[1], bo2 = b_out[2];

    // ---- prologue: gi^T = W_ih * x^T, per batch-chunk q, in D layout ----
    f32x4 initR[4], initZ[4], giN[4];
    #pragma unroll
    for (int q = 0; q < 4; ++q) { initR[q] = bR4; initZ[q] = bZ4; giN[q] = bN4i; }
    #pragma unroll
    for (int kt = 0; kt < 8; ++kt) {
        short8 a0 = cvt8(W_ih + (size_t)(      hb + l15) * 256 + kt * 32 + l4 * 8);
        short8 a1 = cvt8(W_ih + (size_t)(128 + hb + l15) * 256 + kt * 32 + l4 * 8);
        short8 a2 = cvt8(W_ih + (size_t)(256 + hb + l15) * 256 + kt * 32 + l4 * 8);
        #pragma unroll
        for (int q = 0; q < 4; ++q) {
            short8 bx = cvt8(x + (size_t)(b0 + q * 16 + l15) * 256 + kt * 32 + l4 * 8);
            initR[q] = MFMA16(a0, bx, initR[q]);
            initZ[q] = MFMA16(a1, bx, initZ[q]);
            giN [q] = MFMA16(a2, bx, giN [q]);
        }
    }

    float hq[4][4];
    #pragma unroll
    for (int q = 0; q < 4; ++q)
        #pragma unroll
        for (int r = 0; r < 4; ++r) hq[q][r] = 0.f;

    const int s8  = (wid << 2) | l4;            // lane's 8B slot (hid/4) in a row
    const int wsw = (((s8 >> 1) ^ l15) & 15);   // swizzled 16B chunk for write

    __syncthreads();

    #pragma unroll 2
    for (int t = 0; t < 60; ++t) {
        const short* rb = hbuf[t & 1];
        short*       wb = hbuf[(t & 1) ^ 1];
        #pragma unroll
        for (int q = 0; q < 4; ++q) {
            // B-frags: B[k][n=l15] = h[batch q*16+l15][hid k], swizzled chunks
            short8 af[4];
            #pragma unroll
            for (int kt = 0; kt < 4; ++kt)
                af[kt] = *(const short8*)(rb + (q * 16 + l15) * 128 + (((kt * 4 + l4) ^ l15) & 15) * 8);

            // output head for h_t (out column t-1), rotated across waves; reuses af
            if (t > 0 && wid == ((q + t) & 7)) {
                f32x4 oa = (f32x4){0.f, 0.f, 0.f, 0.f};
                #pragma unroll
                for (int kt = 0; kt < 4; ++kt) {
                    short8 wo = {0, 0, 0, 0, 0, 0, 0, 0};
                    if (l15 < 3) wo = *(const short8*)(wobuf + l15 * 136 + kt * 32 + l4 * 8);
                    oa = MFMA16(wo, af[kt], oa);
                }
                if (l4 == 0) {
                    float* op = out + (size_t)(b0 + q * 16 + l15) * 180 + (t - 1) * 3;
                    op[0] = oa[0] + bo0; op[1] = oa[1] + bo1; op[2] = oa[2] + bo2;
                }
            }

            // gh^T = W_hh * h^T (+ bias C-init)
            f32x4 aR = initR[q], aZ = initZ[q], aN = bN4h;
            #pragma unroll
            for (int kt = 0; kt < 4; ++kt) {
                aR = MFMA16(wfrag[0][kt], af[kt], aR);
                aZ = MFMA16(wfrag[1][kt], af[kt], aZ);
                aN = MFMA16(wfrag[2][kt], af[kt], aN);
            }
            // gates; lane holds 4 consecutive hid dims of batch row q*16+l15
            float hn[4];
            #pragma unroll
            for (int r = 0; r < 4; ++r) {
                float rr = fsig(aR[r]);
                float zz = fsig(aZ[r]);
                float nn = ftanh_(giN[q][r] + rr * aN[r]);
                hn[r] = nn + zz * (hq[q][r] - nn);
                hq[q][r] = hn[r];
            }
            uint2 pk;
            pk.x = pk2bf(hn[0], hn[1]);
            pk.y = pk2bf(hn[2], hn[3]);
            *(uint2*)(wb + (q * 16 + l15) * 128 + wsw * 8 + (s8 & 1) * 4) = pk;
        }
        __syncthreads();
    }

    // epilogue: out column 59 from h_60 (in hbuf[0])
    if (wid < 4) {
        const int q = wid;
        const short* rb = hbuf[0];
        f32x4 oa = (f32x4){0.f, 0.f, 0.f, 0.f};
        #pragma unroll
        for (int kt = 0; kt < 4; ++kt) {
            short8 af = *(const short8*)(rb + (q * 16 + l15) * 128 + (((kt * 4 + l4) ^ l15) & 15) * 8);
            short8 wo = {0, 0, 0, 0, 0, 0, 0, 0};
            if (l15 < 3) wo = *(const short8*)(wobuf + l15 * 136 + kt * 32 + l4 * 8);
            oa = MFMA16(wo, af, oa);
        }
        if (l4 == 0) {
            float* op = out + (size_t)(b0 + q * 16 + l15) * 180 + 59 * 3;
            op[0] = oa[0] + bo0; op[1] = oa[1] + bo1; op[2] = oa[2] + bo2;
        }
    }
}

extern "C" void kernel_launch(void* const* d_in, const int* in_sizes, int n_in,
                              void* d_out, int out_size, void* d_ws, size_t ws_size,
                              hipStream_t stream) {
    const float* x     = (const float*)d_in[0];
    const float* W_ih  = (const float*)d_in[1];
    const float* W_hh  = (const float*)d_in[2];
    const float* b_ih  = (const float*)d_in[3];
    const float* b_hh  = (const float*)d_in[4];
    const float* W_out = (const float*)d_in[5];
    const float* b_out = (const float*)d_in[6];
    float* out = (float*)d_out;

    const int B = in_sizes[0] / 256;   // 16384
    hipLaunchKernelGGL(gru_traj_kernel, dim3(B / 64), dim3(512), 0, stream,
                       x, W_ih, W_hh, b_ih, b_hh, W_out, b_out, out);
}